// Round 14
// baseline (189.922 us; speedup 1.0000x reference)
//
#include <hip/hip_runtime.h>
#include <hip/hip_bf16.h>

#define S_LEN 4096
#define NH 4
#define HD 256
#define WIN 512
#define ATT_SCALE 0.0625f   // 256^-0.5
#define QKV_N 1536          // packed q(1024) | k(256) | v(256)

typedef short s16x8 __attribute__((ext_vector_type(8)));
typedef float f32x4 __attribute__((ext_vector_type(4)));

static __device__ inline unsigned short f2bf(float f) {
  union { float f; unsigned int u; } v; v.f = f;
  unsigned int r = v.u + 0x7fff + ((v.u >> 16) & 1);   // RNE
  return (unsigned short)(r >> 16);
}
static __device__ inline float bf2f(unsigned short h) {
  union { unsigned int u; float f; } v; v.u = ((unsigned int)h) << 16;
  return v.f;
}
static __device__ inline void gl2lds16(const void* g, void* l) {
  __builtin_amdgcn_global_load_lds(
      (const __attribute__((address_space(1))) unsigned int*)g,
      (__attribute__((address_space(3))) unsigned int*)l, 16, 0, 0);
}

// ---------------------------------------------------------------------------
// Fused prep: region [0,5120) = x fp32->bf16 cast; then 4 transpose+cast
// weight regions (Wq,Wk,Wv -> packed Wqkvt; Wo -> Wot). One dispatch.
// ---------------------------------------------------------------------------
static __device__ void trcast_tile(const float* __restrict__ src,
                                   unsigned short* __restrict__ dst,
                                   int K, int N, int bn, int bk, int tid,
                                   float* ts /*[64][65]*/) {
#pragma unroll
  for (int it = 0; it < 4; ++it) {
    const int c = it * 256 + tid;
    const int row = c >> 4, col4 = (c & 15) << 2;
    const float4 v = *(const float4*)(src + (size_t)(bk * 64 + row) * N + bn * 64 + col4);
    ts[row * 65 + col4 + 0] = v.x; ts[row * 65 + col4 + 1] = v.y;
    ts[row * 65 + col4 + 2] = v.z; ts[row * 65 + col4 + 3] = v.w;
  }
  __syncthreads();
#pragma unroll
  for (int it = 0; it < 4; ++it) {
    const int c = it * 256 + tid;
    const int nrow = c >> 4, kc4 = (c & 15) << 2;
    const unsigned int p0 = f2bf(ts[(kc4 + 0) * 65 + nrow]) | ((unsigned int)f2bf(ts[(kc4 + 1) * 65 + nrow]) << 16);
    const unsigned int p1 = f2bf(ts[(kc4 + 2) * 65 + nrow]) | ((unsigned int)f2bf(ts[(kc4 + 3) * 65 + nrow]) << 16);
    *(uint2*)(dst + (size_t)(bn * 64 + nrow) * K + bk * 64 + kc4) = make_uint2(p0, p1);
  }
}

__global__ __launch_bounds__(256) void prep_kernel(
    const float* __restrict__ x, unsigned short* __restrict__ xb,
    const float* __restrict__ Wq, const float* __restrict__ Wk,
    const float* __restrict__ Wv, const float* __restrict__ Wo,
    unsigned short* __restrict__ Wqkvt, unsigned short* __restrict__ Wot) {
  __shared__ float ts[64 * 65];
  const int g = blockIdx.x;
  const int tid = threadIdx.x;
  if (g < 5120) {                    // cvt x -> bf16 (1310720 float4 elems)
    const int t = g * 256 + tid;
    const float4 v = ((const float4*)x)[t];
    const unsigned int p0 = f2bf(v.x) | ((unsigned int)f2bf(v.y) << 16);
    const unsigned int p1 = f2bf(v.z) | ((unsigned int)f2bf(v.w) << 16);
    *(uint2*)(xb + (size_t)t * 4) = make_uint2(p0, p1);
  } else if (g < 5280) {             // Wq: N=1024 (16), K=640 (10)
    const int g2 = g - 5120;
    trcast_tile(Wq, Wqkvt, 640, 1024, g2 & 15, g2 >> 4, tid, ts);
  } else if (g < 5320) {             // Wk: N=256 (4), K=640 (10)
    const int g2 = g - 5280;
    trcast_tile(Wk, Wqkvt + (size_t)1024 * 640, 640, 256, g2 & 3, g2 >> 2, tid, ts);
  } else if (g < 5360) {             // Wv
    const int g2 = g - 5320;
    trcast_tile(Wv, Wqkvt + (size_t)1280 * 640, 640, 256, g2 & 3, g2 >> 2, tid, ts);
  } else {                           // Wo: N=640 (10), K=1024 (16)
    const int g2 = g - 5360;
    trcast_tile(Wo, Wot, 1024, 640, g2 % 10, g2 / 10, tid, ts);
  }
}

// ---------------------------------------------------------------------------
// bf16 MFMA GEMM, 128x128 tile, attn-style double-buffered staging:
// stage(t+1) at loop top -> compute(t) -> ONE barrier per K-step. The old
// m97 order (stage(t); barrier; compute(t); barrier) drained the staging
// loads immediately after issue -> full latency exposed every iteration;
// at K=640 (10 iters) that drain doesn't amortize. Now the drain at the
// loop-bottom barrier is covered by the compute of the current tile
// (attn's proven pattern). Barriers: 20 -> 10.
// T1 XCD swizzle: bijective remap (nwg%8==0) so the 12 blocks sharing an
// A-panel land on one XCD's L2.
// ---------------------------------------------------------------------------
template <bool BF16OUT>
__global__ __launch_bounds__(256) void gemm_bt(const unsigned short* __restrict__ A,
                                               const unsigned short* __restrict__ Bt,
                                               void* __restrict__ Cv,
                                               int M, int N, int K) {
  __shared__ unsigned short As[2][128 * 32];
  __shared__ unsigned short Bs[2][128 * 32];
  const int tid = threadIdx.x;
  const int wave = tid >> 6, lane = tid & 63;
  const int ln15 = lane & 15, lgr = lane >> 4;
  const int nbn = gridDim.x;
  const int lin = blockIdx.y * nbn + blockIdx.x;
  const int cpx = (gridDim.x * gridDim.y) >> 3;   // blocks per XCD
  const int swz = (lin & 7) * cpx + (lin >> 3);   // bijective when nwg%8==0
  const int bm = swz / nbn, bn = swz % nbn;
  const int wr = wave & 1, wc = wave >> 1;
  const unsigned short* Ab = A + (size_t)bm * 128 * K;
  const unsigned short* Bb = Bt + (size_t)bn * 128 * K;

  f32x4 acc[4][4];
#pragma unroll
  for (int mt = 0; mt < 4; ++mt)
#pragma unroll
    for (int nt = 0; nt < 4; ++nt) acc[mt][nt] = (f32x4){0.f, 0.f, 0.f, 0.f};

  auto stage = [&](int kt, int buf) {
#pragma unroll
    for (int i = 0; i < 2; ++i) {
      const int c = tid + 256 * i;
      const int row = c >> 2, kc = (c & 3) << 3;
      gl2lds16(Ab + (size_t)row * K + kt + kc, &As[buf][c * 8]);
      gl2lds16(Bb + (size_t)row * K + kt + kc, &Bs[buf][c * 8]);
    }
  };

  stage(0, 0);
  __syncthreads();

  const int nkt = K >> 5;
  for (int t = 0; t < nkt; ++t) {
    const int cur = t & 1;
    if (t + 1 < nkt) stage((t + 1) << 5, cur ^ 1);
    s16x8 af[4], bfr[4];
#pragma unroll
    for (int u = 0; u < 4; ++u) {
      af[u]  = *(const s16x8*)&As[cur][(wr * 64 + u * 16 + ln15) * 32 + lgr * 8];
      bfr[u] = *(const s16x8*)&Bs[cur][(wc * 64 + u * 16 + ln15) * 32 + lgr * 8];
    }
#pragma unroll
    for (int mt = 0; mt < 4; ++mt)
#pragma unroll
      for (int nt = 0; nt < 4; ++nt)
        acc[mt][nt] = __builtin_amdgcn_mfma_f32_16x16x32_bf16(af[mt], bfr[nt], acc[mt][nt], 0, 0, 0);
    __syncthreads();
  }

#pragma unroll
  for (int mt = 0; mt < 4; ++mt)
#pragma unroll
    for (int nt = 0; nt < 4; ++nt)
#pragma unroll
      for (int r = 0; r < 4; ++r) {
        const size_t row = bm * 128 + wr * 64 + mt * 16 + lgr * 4 + r;
        const size_t col = bn * 128 + wc * 64 + nt * 16 + ln15;
        if (BF16OUT) ((unsigned short*)Cv)[row * N + col] = f2bf(acc[mt][nt][r]);
        else         ((float*)Cv)[row * N + col] = acc[mt][nt][r];
      }
}

// ---------------------------------------------------------------------------
// 64x128-tile variant (fp32 out) for the output projection, same dbuf
// structure: barriers 32 -> 16 at K=1024. Grid 128x5 = 640, XCD-swizzled.
// LDS 40KB -> 4 blocks/CU.
// ---------------------------------------------------------------------------
__global__ __launch_bounds__(256) void gemm_bt64(const unsigned short* __restrict__ A,
                                                 const unsigned short* __restrict__ Bt,
                                                 float* __restrict__ C,
                                                 int M, int N, int K) {
  __shared__ unsigned short As[2][64 * 32];
  __shared__ unsigned short Bs[2][128 * 32];
  const int tid = threadIdx.x;
  const int wave = tid >> 6, lane = tid & 63;
  const int ln15 = lane & 15, lgr = lane >> 4;
  const int nbn = gridDim.x;
  const int lin = blockIdx.y * nbn + blockIdx.x;
  const int cpx = (gridDim.x * gridDim.y) >> 3;
  const int swz = (lin & 7) * cpx + (lin >> 3);
  const int bm = swz / nbn, bn = swz % nbn;
  const unsigned short* Ab = A + (size_t)bm * 64 * K;
  const unsigned short* Bb = Bt + (size_t)bn * 128 * K;

  f32x4 acc[4][2];
#pragma unroll
  for (int mt = 0; mt < 4; ++mt)
#pragma unroll
    for (int nt = 0; nt < 2; ++nt) acc[mt][nt] = (f32x4){0.f, 0.f, 0.f, 0.f};

  auto stage = [&](int kt, int buf) {
    {
      const int row = tid >> 2, kc = (tid & 3) << 3;
      gl2lds16(Ab + (size_t)row * K + kt + kc, &As[buf][tid * 8]);
    }
#pragma unroll
    for (int i = 0; i < 2; ++i) {
      const int c = tid + 256 * i;
      const int brow = c >> 2, bkc = (c & 3) << 3;
      gl2lds16(Bb + (size_t)brow * K + kt + bkc, &Bs[buf][c * 8]);
    }
  };

  stage(0, 0);
  __syncthreads();

  const int nkt = K >> 5;
  for (int t = 0; t < nkt; ++t) {
    const int cur = t & 1;
    if (t + 1 < nkt) stage((t + 1) << 5, cur ^ 1);
    s16x8 af[4], bfr[2];
#pragma unroll
    for (int u = 0; u < 4; ++u)
      af[u] = *(const s16x8*)&As[cur][(u * 16 + ln15) * 32 + lgr * 8];
#pragma unroll
    for (int u = 0; u < 2; ++u)
      bfr[u] = *(const s16x8*)&Bs[cur][(wave * 32 + u * 16 + ln15) * 32 + lgr * 8];
#pragma unroll
    for (int mt = 0; mt < 4; ++mt)
#pragma unroll
      for (int nt = 0; nt < 2; ++nt)
        acc[mt][nt] = __builtin_amdgcn_mfma_f32_16x16x32_bf16(af[mt], bfr[nt], acc[mt][nt], 0, 0, 0);
    __syncthreads();
  }

#pragma unroll
  for (int mt = 0; mt < 4; ++mt)
#pragma unroll
    for (int nt = 0; nt < 2; ++nt)
#pragma unroll
      for (int r = 0; r < 4; ++r) {
        const size_t row = bm * 64 + mt * 16 + lgr * 4 + r;
        const size_t col = bn * 128 + wave * 32 + nt * 16 + ln15;
        C[row * N + col] = acc[mt][nt][r];
      }
}

// ---------------------------------------------------------------------------
// Fused RMSNorm+RoPE (blocks [0,10240)) + V-transpose (blocks [10240,10496)).
// (R6 verified config: Q-fusion into attn abandoned after two VGPR-cliff
// regressions, R8/R10.)
//
// Norm part wave-per-row: one wave = one 256-elem row, 4 elems/lane via uint2,
// wave-local shfl reduce only -- zero barriers, zero LDS, 4 rows per block.
//
// V-transpose uses INTERLEAVED key storage order s = 2*(jj&15) | (jj>>4), so
// attention's P round-trip can write packed b32 pairs (PV is key-permutation
// invariant as long as P cols and Vt cols share the order).
// ---------------------------------------------------------------------------
__global__ __launch_bounds__(256) void normrope_vt_kernel(
    unsigned short* __restrict__ qkv,
    const float* __restrict__ cosb, const float* __restrict__ sinb,
    const float* __restrict__ qw, const float* __restrict__ kw,
    unsigned short* __restrict__ vtb) {
  const int bid = blockIdx.x;
  const int tid = threadIdx.x;
  if (bid < 10240) {
    const int lane = tid & 63, wave = tid >> 6;
    const int idx = bid * 4 + wave;          // 0..40959 (row id)
    const int h = idx % 5;
    const int bs = idx / 5;
    const int s = bs & (S_LEN - 1);
    unsigned short* base = qkv + (size_t)bs * QKV_N;
    unsigned short* row; const float* w; float oscale;
    if (h < 4) { row = base + h * HD;  w = qw; oscale = ATT_SCALE; }
    else       { row = base + 4 * HD;  w = kw; oscale = 1.0f; }
    // lane handles elements [4*lane, 4*lane+4) = rope pairs pi=2*lane, 2*lane+1
    const uint2 pv = *(const uint2*)(row + 4 * lane);
    float xv[4];
    xv[0] = bf2f((unsigned short)(pv.x & 0xffff));
    xv[1] = bf2f((unsigned short)(pv.x >> 16));
    xv[2] = bf2f((unsigned short)(pv.y & 0xffff));
    xv[3] = bf2f((unsigned short)(pv.y >> 16));
    float ssq = xv[0] * xv[0] + xv[1] * xv[1] + xv[2] * xv[2] + xv[3] * xv[3];
#pragma unroll
    for (int off = 32; off > 0; off >>= 1) ssq += __shfl_xor(ssq, off);
    const float inv = rsqrtf(ssq * (1.0f / 256.0f) + 1e-6f);
    const float4 wv = *(const float4*)(w + 4 * lane);
    const float2 cv = *(const float2*)(cosb + (size_t)s * (HD / 2) + 2 * lane);
    const float2 sv = *(const float2*)(sinb + (size_t)s * (HD / 2) + 2 * lane);
    const float a0 = xv[0] * inv * (1.0f + wv.x);
    const float b0 = xv[1] * inv * (1.0f + wv.y);
    const float a1 = xv[2] * inv * (1.0f + wv.z);
    const float b1 = xv[3] * inv * (1.0f + wv.w);
    const float o0 = (a0 * cv.x - b0 * sv.x) * oscale;
    const float o1 = (a0 * sv.x + b0 * cv.x) * oscale;
    const float o2 = (a1 * cv.y - b1 * sv.y) * oscale;
    const float o3 = (a1 * sv.y + b1 * cv.y) * oscale;
    uint2 ov;
    ov.x = (unsigned int)f2bf(o0) | ((unsigned int)f2bf(o1) << 16);
    ov.y = (unsigned int)f2bf(o2) | ((unsigned int)f2bf(o3) << 16);
    *(uint2*)(row + 4 * lane) = ov;
  } else {
    __shared__ unsigned short ts[32][264];
    const int g2 = bid - 10240;
    const int b = g2 >> 7, jt = g2 & 127;
    const unsigned short* src = qkv + ((size_t)(b * S_LEN) + jt * 32) * QKV_N + 5 * HD;
#pragma unroll
    for (int it = 0; it < 4; ++it) {
      const int c = tid + 256 * it;
      const int row = c >> 5, col8 = (c & 31) << 3;
      *(uint4*)&ts[row][col8] = *(const uint4*)(src + (size_t)row * QKV_N + col8);
    }
    __syncthreads();
    unsigned short tmp[32];
#pragma unroll
    for (int s2 = 0; s2 < 32; ++s2) {
      const int jj = (s2 >> 1) | ((s2 & 1) << 4);   // inverse of s = 2*(jj&15)|(jj>>4)
      tmp[s2] = ts[jj][tid];
    }
    unsigned short* dst = vtb + ((size_t)(b * 128 + jt) * 256 + tid) * 32;
#pragma unroll
    for (int wq = 0; wq < 4; ++wq) *(uint4*)(dst + wq * 8) = *(uint4*)(tmp + wq * 8);
  }
}

// ---------------------------------------------------------------------------
// Flash-style sliding-window MQA, bf16 MFMA — verified R6 structure (88 VGPR,
// 2 blocks/CU) + T5 s_setprio around MFMA clusters (within noise, kept).
// LOCKED: R1 V-direct, R4 key-split, R8/R10 Q-fusion all regressed.
// ---------------------------------------------------------------------------
#define PS_LD 40

__global__ __launch_bounds__(256) void attn_mfma_kernel(
    const unsigned short* __restrict__ qkv, const unsigned short* __restrict__ vtb,
    unsigned short* __restrict__ aob) {
  const int g = blockIdx.x;
  const int xcd = g & 7, slot = g >> 3;      // assume block j -> XCD j%8
  const int h = slot >> 4;                   // 0..3
  const int qt = xcd * 16 + (slot & 15);     // 0..127
  const int b = qt >> 6;
  const int q0 = (qt & 63) << 6;
  const int tid = threadIdx.x;
  const int wave = tid >> 6;
  const int lane = tid & 63;
  const int ln15 = lane & 15;
  const int lgr = lane >> 4;

  __shared__ unsigned short Ks[2][16 * 512];
  __shared__ unsigned short Vts[2][16 * 512];
  __shared__ unsigned short Ps[4][16 * PS_LD];

  const size_t qrow = (size_t)(b * S_LEN + q0 + wave * 16 + ln15) * QKV_N + h * HD;
  s16x8 qfrag[8];
#pragma unroll
  for (int f = 0; f < 8; ++f)
    qfrag[f] = *(const s16x8*)(qkv + qrow + f * 32 + lgr * 8);

  f32x4 acc[16];
#pragma unroll
  for (int t = 0; t < 16; ++t) acc[t] = (f32x4){0.f, 0.f, 0.f, 0.f};
  float l_part[4] = {0.f, 0.f, 0.f, 0.f};

  const int kt_lo = max(0, q0 - WIN) >> 5;
  const int kt_hi = (q0 + 63) >> 5;
  const unsigned short* kbase = qkv + (size_t)(b * S_LEN) * QKV_N + 4 * HD;
  const unsigned short* vbase = vtb + (size_t)b * (S_LEN / 32) * HD * 32;

  auto stage = [&](int kt, int buf) {
#pragma unroll
    for (int u = 0; u < 4; ++u) {
      const int c = wave * 4 + u;
      const int ct = c >> 3, f = c & 7;
      const unsigned short* gk =
          kbase + (size_t)(kt * 32 + ct * 16 + ln15) * QKV_N + f * 32 + lgr * 8;
      gl2lds16(gk, &Ks[buf][c * 512]);
      const unsigned short* gv =
          vbase + (size_t)kt * (HD * 32) + (size_t)(c * 16 + ln15) * 32 + lgr * 8;
      gl2lds16(gv, &Vts[buf][c * 512]);
    }
  };

  stage(kt_lo, 0);
  __syncthreads();

  unsigned short* psw = Ps[wave];
  const int i_row0 = q0 + wave * 16 + lgr * 4;

  for (int kt = kt_lo; kt <= kt_hi; ++kt) {
    const int cur = (kt - kt_lo) & 1;
    if (kt < kt_hi) stage(kt + 1, cur ^ 1);

    // QK^T
    f32x4 sc[2];
    sc[0] = (f32x4){0.f, 0.f, 0.f, 0.f};
    sc[1] = (f32x4){0.f, 0.f, 0.f, 0.f};
    __builtin_amdgcn_s_setprio(1);
#pragma unroll
    for (int f = 0; f < 8; ++f) {
#pragma unroll
      for (int ct = 0; ct < 2; ++ct) {
        const s16x8 kf = *(const s16x8*)&Ks[cur][(ct * 8 + f) * 512 + lane * 8];
        sc[ct] = __builtin_amdgcn_mfma_f32_16x16x32_bf16(qfrag[f], kf, sc[ct], 0, 0, 0);
      }
    }
    __builtin_amdgcn_s_setprio(0);

    // static-max softmax: p = exp(s - 16), masked to 0
    const int j0 = kt * 32 + ln15;
    float p0[4], p1[4];
#pragma unroll
    for (int r = 0; r < 4; ++r) {
      const int i = i_row0 + r;
      const bool a0 = (j0 <= i) && (i - j0 <= WIN);
      const bool a1 = (j0 + 16 <= i) && (i - (j0 + 16) <= WIN);
      const float e0 = __expf(sc[0][r] - 16.0f);
      const float e1 = __expf(sc[1][r] - 16.0f);
      p0[r] = a0 ? e0 : 0.0f;
      p1[r] = a1 ? e1 : 0.0f;
      l_part[r] += p0[r] + p1[r];
    }
    // packed b32 P writes: col 2*ln15 = key ln15 (ct0), col 2*ln15+1 = key 16+ln15
#pragma unroll
    for (int r = 0; r < 4; ++r) {
      const unsigned int pk = (unsigned int)f2bf(p0[r]) | ((unsigned int)f2bf(p1[r]) << 16);
      *(unsigned int*)&psw[(lgr * 4 + r) * PS_LD + (ln15 << 1)] = pk;
    }
    const s16x8 pf = *(const s16x8*)&psw[ln15 * PS_LD + lgr * 8];
    __builtin_amdgcn_s_setprio(1);
#pragma unroll
    for (int t = 0; t < 16; ++t) {
      const s16x8 vf = *(const s16x8*)&Vts[cur][t * 512 + lane * 8];
      acc[t] = __builtin_amdgcn_mfma_f32_16x16x32_bf16(pf, vf, acc[t], 0, 0, 0);
    }
    __builtin_amdgcn_s_setprio(0);
    __syncthreads();
  }

#pragma unroll
  for (int off = 1; off < 16; off <<= 1)
#pragma unroll
    for (int r = 0; r < 4; ++r) l_part[r] += __shfl_xor(l_part[r], off);

  float inv_l[4];
#pragma unroll
  for (int r = 0; r < 4; ++r) inv_l[r] = 1.0f / l_part[r];
#pragma unroll
  for (int t = 0; t < 16; ++t)
#pragma unroll
    for (int r = 0; r < 4; ++r) {
      const size_t orow = (size_t)(b * S_LEN + q0 + wave * 16 + lgr * 4 + r);
      aob[(orow * NH + h) * HD + t * 16 + ln15] = f2bf(acc[t][r] * inv_l[r]);
    }
}

// ---------------------------------------------------------------------------
extern "C" void kernel_launch(void* const* d_in, const int* in_sizes, int n_in,
                              void* d_out, int out_size, void* d_ws, size_t ws_size,
                              hipStream_t stream) {
  const float* x    = (const float*)d_in[0];
  const float* cosb = (const float*)d_in[1];
  const float* sinb = (const float*)d_in[2];
  const float* Wq   = (const float*)d_in[3];
  const float* Wk   = (const float*)d_in[4];
  const float* Wv   = (const float*)d_in[5];
  const float* Wo   = (const float*)d_in[6];
  const float* qw   = (const float*)d_in[7];
  const float* kw   = (const float*)d_in[8];
  float* out = (float*)d_out;

  unsigned short* ws = (unsigned short*)d_ws;
  unsigned short* xb     = ws;                    // 8192*640  = 5242880
  unsigned short* Wqkvt  = xb + 5242880;          // 1536*640  = 983040
  unsigned short* Wot    = Wqkvt + 983040;        // 640*1024  = 655360
  unsigned short* qkvb   = Wot + 655360;          // 8192*1536 = 12582912
  unsigned short* vtb    = qkvb + 12582912;       // 8192*256  = 2097152
  unsigned short* aob    = vtb + 2097152;         // 8192*1024 = 8388608
  const int M = 2 * S_LEN;

  prep_kernel<<<5520, 256, 0, stream>>>(x, xb, Wq, Wk, Wv, Wo, Wqkvt, Wot);
  gemm_bt<true><<<dim3(QKV_N / 128, M / 128), 256, 0, stream>>>(xb, Wqkvt, qkvb, M, QKV_N, 640);
  normrope_vt_kernel<<<10240 + 256, 256, 0, stream>>>(qkvb, cosb, sinb, qw, kw, vtb);
  attn_mfma_kernel<<<M / 64 * NH, 256, 0, stream>>>(qkvb, vtb, aob);
  gemm_bt64<<<dim3(640 / 128, M / 64), 256, 0, stream>>>(aob, Wot, out, M, 640, 1024);
}

// Round 22
// 188.139 us; speedup vs baseline: 1.0095x; 1.0095x over previous
//
#include <hip/hip_runtime.h>
#include <hip/hip_bf16.h>

#define S_LEN 4096
#define NH 4
#define HD 256
#define WIN 512
#define ATT_SCALE 0.0625f   // 256^-0.5
#define QKV_N 1536          // packed q(1024) | k(256) | v(256)

typedef short s16x8 __attribute__((ext_vector_type(8)));
typedef float f32x4 __attribute__((ext_vector_type(4)));

static __device__ inline unsigned short f2bf(float f) {
  union { float f; unsigned int u; } v; v.f = f;
  unsigned int r = v.u + 0x7fff + ((v.u >> 16) & 1);   // RNE
  return (unsigned short)(r >> 16);
}
static __device__ inline float bf2f(unsigned short h) {
  union { unsigned int u; float f; } v; v.u = ((unsigned int)h) << 16;
  return v.f;
}
static __device__ inline void gl2lds16(const void* g, void* l) {
  __builtin_amdgcn_global_load_lds(
      (const __attribute__((address_space(1))) unsigned int*)g,
      (__attribute__((address_space(3))) unsigned int*)l, 16, 0, 0);
}

// ---------------------------------------------------------------------------
// Fused prep: region [0,5120) = x fp32->bf16 cast; then 4 transpose+cast
// weight regions (Wq,Wk,Wv -> packed Wqkvt; Wo -> Wot). One dispatch.
// ---------------------------------------------------------------------------
static __device__ void trcast_tile(const float* __restrict__ src,
                                   unsigned short* __restrict__ dst,
                                   int K, int N, int bn, int bk, int tid,
                                   float* ts /*[64][65]*/) {
#pragma unroll
  for (int it = 0; it < 4; ++it) {
    const int c = it * 256 + tid;
    const int row = c >> 4, col4 = (c & 15) << 2;
    const float4 v = *(const float4*)(src + (size_t)(bk * 64 + row) * N + bn * 64 + col4);
    ts[row * 65 + col4 + 0] = v.x; ts[row * 65 + col4 + 1] = v.y;
    ts[row * 65 + col4 + 2] = v.z; ts[row * 65 + col4 + 3] = v.w;
  }
  __syncthreads();
#pragma unroll
  for (int it = 0; it < 4; ++it) {
    const int c = it * 256 + tid;
    const int nrow = c >> 4, kc4 = (c & 15) << 2;
    const unsigned int p0 = f2bf(ts[(kc4 + 0) * 65 + nrow]) | ((unsigned int)f2bf(ts[(kc4 + 1) * 65 + nrow]) << 16);
    const unsigned int p1 = f2bf(ts[(kc4 + 2) * 65 + nrow]) | ((unsigned int)f2bf(ts[(kc4 + 3) * 65 + nrow]) << 16);
    *(uint2*)(dst + (size_t)(bn * 64 + nrow) * K + bk * 64 + kc4) = make_uint2(p0, p1);
  }
}

__global__ __launch_bounds__(256) void prep_kernel(
    const float* __restrict__ x, unsigned short* __restrict__ xb,
    const float* __restrict__ Wq, const float* __restrict__ Wk,
    const float* __restrict__ Wv, const float* __restrict__ Wo,
    unsigned short* __restrict__ Wqkvt, unsigned short* __restrict__ Wot) {
  __shared__ float ts[64 * 65];
  const int g = blockIdx.x;
  const int tid = threadIdx.x;
  if (g < 5120) {                    // cvt x -> bf16 (1310720 float4 elems)
    const int t = g * 256 + tid;
    const float4 v = ((const float4*)x)[t];
    const unsigned int p0 = f2bf(v.x) | ((unsigned int)f2bf(v.y) << 16);
    const unsigned int p1 = f2bf(v.z) | ((unsigned int)f2bf(v.w) << 16);
    *(uint2*)(xb + (size_t)t * 4) = make_uint2(p0, p1);
  } else if (g < 5280) {             // Wq: N=1024 (16), K=640 (10)
    const int g2 = g - 5120;
    trcast_tile(Wq, Wqkvt, 640, 1024, g2 & 15, g2 >> 4, tid, ts);
  } else if (g < 5320) {             // Wk: N=256 (4), K=640 (10)
    const int g2 = g - 5280;
    trcast_tile(Wk, Wqkvt + (size_t)1024 * 640, 640, 256, g2 & 3, g2 >> 2, tid, ts);
  } else if (g < 5360) {             // Wv
    const int g2 = g - 5320;
    trcast_tile(Wv, Wqkvt + (size_t)1280 * 640, 640, 256, g2 & 3, g2 >> 2, tid, ts);
  } else {                           // Wo: N=640 (10), K=1024 (16)
    const int g2 = g - 5360;
    trcast_tile(Wo, Wot, 1024, 640, g2 % 10, g2 / 10, tid, ts);
  }
}

// ---------------------------------------------------------------------------
// bf16 MFMA GEMM (m97 structure + BK=64 slab staging): C = A @ Bt^T, 128x128.
// BK=64 as TWO independent [128][32] slabs: each slab keeps the proven LDS
// layout / fragment-read pattern (gl2lds dest must stay linear, m104; a
// [128][64] tile would be a 16-way bank conflict, m201). Halves the
// per-K-step barrier+vmcnt(0)-drain count: 40 -> 20 barriers at K=640.
// R14 A/B: attn-style dbuf (1 barrier/32-K) was ~8us WORSE at matched
// clocks -- GEMM compute/barrier (~80cyc) can't cover load latency, so the
// prefetch drain exposes anyway; slabs give 32 uninterrupted MFMA per drain.
// T1 XCD swizzle: bijective remap (nwg%8==0) so the 12 blocks sharing an
// A-panel land on one XCD's L2.
// ---------------------------------------------------------------------------
template <bool BF16OUT>
__global__ __launch_bounds__(256) void gemm_bt(const unsigned short* __restrict__ A,
                                               const unsigned short* __restrict__ Bt,
                                               void* __restrict__ Cv,
                                               int M, int N, int K) {
  __shared__ unsigned short As[2][128 * 32];
  __shared__ unsigned short Bs[2][128 * 32];
  const int tid = threadIdx.x;
  const int wave = tid >> 6, lane = tid & 63;
  const int ln15 = lane & 15, lgr = lane >> 4;
  const int nbn = gridDim.x;
  const int lin = blockIdx.y * nbn + blockIdx.x;
  const int cpx = (gridDim.x * gridDim.y) >> 3;   // blocks per XCD
  const int swz = (lin & 7) * cpx + (lin >> 3);   // bijective when nwg%8==0
  const int bm = swz / nbn, bn = swz % nbn;
  const int wr = wave & 1, wc = wave >> 1;
  const unsigned short* Ab = A + (size_t)bm * 128 * K;
  const unsigned short* Bb = Bt + (size_t)bn * 128 * K;

  f32x4 acc[4][4];
#pragma unroll
  for (int mt = 0; mt < 4; ++mt)
#pragma unroll
    for (int nt = 0; nt < 4; ++nt) acc[mt][nt] = (f32x4){0.f, 0.f, 0.f, 0.f};

  for (int kt = 0; kt < K; kt += 64) {
#pragma unroll
    for (int s = 0; s < 2; ++s)
#pragma unroll
      for (int i = 0; i < 2; ++i) {
        const int c = tid + 256 * i;
        const int row = c >> 2, kc = (c & 3) << 3;
        gl2lds16(Ab + (size_t)row * K + kt + s * 32 + kc, &As[s][c * 8]);
        gl2lds16(Bb + (size_t)row * K + kt + s * 32 + kc, &Bs[s][c * 8]);
      }
    __syncthreads();
#pragma unroll
    for (int s = 0; s < 2; ++s) {
      s16x8 af[4], bfr[4];
#pragma unroll
      for (int t = 0; t < 4; ++t) {
        af[t]  = *(const s16x8*)&As[s][(wr * 64 + t * 16 + ln15) * 32 + lgr * 8];
        bfr[t] = *(const s16x8*)&Bs[s][(wc * 64 + t * 16 + ln15) * 32 + lgr * 8];
      }
#pragma unroll
      for (int mt = 0; mt < 4; ++mt)
#pragma unroll
        for (int nt = 0; nt < 4; ++nt)
          acc[mt][nt] = __builtin_amdgcn_mfma_f32_16x16x32_bf16(af[mt], bfr[nt], acc[mt][nt], 0, 0, 0);
    }
    __syncthreads();
  }

#pragma unroll
  for (int mt = 0; mt < 4; ++mt)
#pragma unroll
    for (int nt = 0; nt < 4; ++nt)
#pragma unroll
      for (int r = 0; r < 4; ++r) {
        const size_t row = bm * 128 + wr * 64 + mt * 16 + lgr * 4 + r;
        const size_t col = bn * 128 + wc * 64 + nt * 16 + ln15;
        if (BF16OUT) ((unsigned short*)Cv)[row * N + col] = f2bf(acc[mt][nt][r]);
        else         ((float*)Cv)[row * N + col] = acc[mt][nt][r];
      }
}

// ---------------------------------------------------------------------------
// 64x128-tile variant (fp32 out) for the output projection, BK=64 slabs:
// barriers 64 -> 32 at K=1024. Grid 128x5 = 640 blocks, XCD-swizzled.
// ---------------------------------------------------------------------------
__global__ __launch_bounds__(256) void gemm_bt64(const unsigned short* __restrict__ A,
                                                 const unsigned short* __restrict__ Bt,
                                                 float* __restrict__ C,
                                                 int M, int N, int K) {
  __shared__ unsigned short As[2][64 * 32];
  __shared__ unsigned short Bs[2][128 * 32];
  const int tid = threadIdx.x;
  const int wave = tid >> 6, lane = tid & 63;
  const int ln15 = lane & 15, lgr = lane >> 4;
  const int nbn = gridDim.x;
  const int lin = blockIdx.y * nbn + blockIdx.x;
  const int cpx = (gridDim.x * gridDim.y) >> 3;
  const int swz = (lin & 7) * cpx + (lin >> 3);
  const int bm = swz / nbn, bn = swz % nbn;
  const unsigned short* Ab = A + (size_t)bm * 64 * K;
  const unsigned short* Bb = Bt + (size_t)bn * 128 * K;

  f32x4 acc[4][2];
#pragma unroll
  for (int mt = 0; mt < 4; ++mt)
#pragma unroll
    for (int nt = 0; nt < 2; ++nt) acc[mt][nt] = (f32x4){0.f, 0.f, 0.f, 0.f};

  for (int kt = 0; kt < K; kt += 64) {
#pragma unroll
    for (int s = 0; s < 2; ++s) {
      const int row = tid >> 2, kc = (tid & 3) << 3;
      gl2lds16(Ab + (size_t)row * K + kt + s * 32 + kc, &As[s][tid * 8]);
#pragma unroll
      for (int i = 0; i < 2; ++i) {
        const int c = tid + 256 * i;
        const int brow = c >> 2, bkc = (c & 3) << 3;
        gl2lds16(Bb + (size_t)brow * K + kt + s * 32 + bkc, &Bs[s][c * 8]);
      }
    }
    __syncthreads();
#pragma unroll
    for (int s = 0; s < 2; ++s) {
      s16x8 af[4], bfr[2];
#pragma unroll
      for (int t = 0; t < 4; ++t)
        af[t] = *(const s16x8*)&As[s][(t * 16 + ln15) * 32 + lgr * 8];
#pragma unroll
      for (int t = 0; t < 2; ++t)
        bfr[t] = *(const s16x8*)&Bs[s][(wave * 32 + t * 16 + ln15) * 32 + lgr * 8];
#pragma unroll
      for (int mt = 0; mt < 4; ++mt)
#pragma unroll
        for (int nt = 0; nt < 2; ++nt)
          acc[mt][nt] = __builtin_amdgcn_mfma_f32_16x16x32_bf16(af[mt], bfr[nt], acc[mt][nt], 0, 0, 0);
    }
    __syncthreads();
  }

#pragma unroll
  for (int mt = 0; mt < 4; ++mt)
#pragma unroll
    for (int nt = 0; nt < 2; ++nt)
#pragma unroll
      for (int r = 0; r < 4; ++r) {
        const size_t row = bm * 64 + mt * 16 + lgr * 4 + r;
        const size_t col = bn * 128 + wave * 32 + nt * 16 + ln15;
        C[row * N + col] = acc[mt][nt][r];
      }
}

// ---------------------------------------------------------------------------
// Fused RMSNorm+RoPE (blocks [0,10240)) + V-transpose (blocks [10240,10496)).
// (R6 verified config: Q-fusion into attn abandoned after two VGPR-cliff
// regressions, R8/R10.)
//
// Norm part wave-per-row: one wave = one 256-elem row, 4 elems/lane via uint2,
// wave-local shfl reduce only -- zero barriers, zero LDS, 4 rows per block.
//
// V-transpose uses INTERLEAVED key storage order s = 2*(jj&15) | (jj>>4), so
// attention's P round-trip can write packed b32 pairs (PV is key-permutation
// invariant as long as P cols and Vt cols share the order).
// ---------------------------------------------------------------------------
__global__ __launch_bounds__(256) void normrope_vt_kernel(
    unsigned short* __restrict__ qkv,
    const float* __restrict__ cosb, const float* __restrict__ sinb,
    const float* __restrict__ qw, const float* __restrict__ kw,
    unsigned short* __restrict__ vtb) {
  const int bid = blockIdx.x;
  const int tid = threadIdx.x;
  if (bid < 10240) {
    const int lane = tid & 63, wave = tid >> 6;
    const int idx = bid * 4 + wave;          // 0..40959 (row id)
    const int h = idx % 5;
    const int bs = idx / 5;
    const int s = bs & (S_LEN - 1);
    unsigned short* base = qkv + (size_t)bs * QKV_N;
    unsigned short* row; const float* w; float oscale;
    if (h < 4) { row = base + h * HD;  w = qw; oscale = ATT_SCALE; }
    else       { row = base + 4 * HD;  w = kw; oscale = 1.0f; }
    // lane handles elements [4*lane, 4*lane+4) = rope pairs pi=2*lane, 2*lane+1
    const uint2 pv = *(const uint2*)(row + 4 * lane);
    float xv[4];
    xv[0] = bf2f((unsigned short)(pv.x & 0xffff));
    xv[1] = bf2f((unsigned short)(pv.x >> 16));
    xv[2] = bf2f((unsigned short)(pv.y & 0xffff));
    xv[3] = bf2f((unsigned short)(pv.y >> 16));
    float ssq = xv[0] * xv[0] + xv[1] * xv[1] + xv[2] * xv[2] + xv[3] * xv[3];
#pragma unroll
    for (int off = 32; off > 0; off >>= 1) ssq += __shfl_xor(ssq, off);
    const float inv = rsqrtf(ssq * (1.0f / 256.0f) + 1e-6f);
    const float4 wv = *(const float4*)(w + 4 * lane);
    const float2 cv = *(const float2*)(cosb + (size_t)s * (HD / 2) + 2 * lane);
    const float2 sv = *(const float2*)(sinb + (size_t)s * (HD / 2) + 2 * lane);
    const float a0 = xv[0] * inv * (1.0f + wv.x);
    const float b0 = xv[1] * inv * (1.0f + wv.y);
    const float a1 = xv[2] * inv * (1.0f + wv.z);
    const float b1 = xv[3] * inv * (1.0f + wv.w);
    const float o0 = (a0 * cv.x - b0 * sv.x) * oscale;
    const float o1 = (a0 * sv.x + b0 * cv.x) * oscale;
    const float o2 = (a1 * cv.y - b1 * sv.y) * oscale;
    const float o3 = (a1 * sv.y + b1 * cv.y) * oscale;
    uint2 ov;
    ov.x = (unsigned int)f2bf(o0) | ((unsigned int)f2bf(o1) << 16);
    ov.y = (unsigned int)f2bf(o2) | ((unsigned int)f2bf(o3) << 16);
    *(uint2*)(row + 4 * lane) = ov;
  } else {
    __shared__ unsigned short ts[32][264];
    const int g2 = bid - 10240;
    const int b = g2 >> 7, jt = g2 & 127;
    const unsigned short* src = qkv + ((size_t)(b * S_LEN) + jt * 32) * QKV_N + 5 * HD;
#pragma unroll
    for (int it = 0; it < 4; ++it) {
      const int c = tid + 256 * it;
      const int row = c >> 5, col8 = (c & 31) << 3;
      *(uint4*)&ts[row][col8] = *(const uint4*)(src + (size_t)row * QKV_N + col8);
    }
    __syncthreads();
    unsigned short tmp[32];
#pragma unroll
    for (int s2 = 0; s2 < 32; ++s2) {
      const int jj = (s2 >> 1) | ((s2 & 1) << 4);   // inverse of s = 2*(jj&15)|(jj>>4)
      tmp[s2] = ts[jj][tid];
    }
    unsigned short* dst = vtb + ((size_t)(b * 128 + jt) * 256 + tid) * 32;
#pragma unroll
    for (int wq = 0; wq < 4; ++wq) *(uint4*)(dst + wq * 8) = *(uint4*)(tmp + wq * 8);
  }
}

// ---------------------------------------------------------------------------
// Flash-style sliding-window MQA, bf16 MFMA — verified R6 structure (88 VGPR,
// 2 blocks/CU) + T5 s_setprio around MFMA clusters (within noise, kept).
// LOCKED: R1 V-direct, R4 key-split, R8/R10 Q-fusion all regressed.
// ---------------------------------------------------------------------------
#define PS_LD 40

__global__ __launch_bounds__(256) void attn_mfma_kernel(
    const unsigned short* __restrict__ qkv, const unsigned short* __restrict__ vtb,
    unsigned short* __restrict__ aob) {
  const int g = blockIdx.x;
  const int xcd = g & 7, slot = g >> 3;      // assume block j -> XCD j%8
  const int h = slot >> 4;                   // 0..3
  const int qt = xcd * 16 + (slot & 15);     // 0..127
  const int b = qt >> 6;
  const int q0 = (qt & 63) << 6;
  const int tid = threadIdx.x;
  const int wave = tid >> 6;
  const int lane = tid & 63;
  const int ln15 = lane & 15;
  const int lgr = lane >> 4;

  __shared__ unsigned short Ks[2][16 * 512];
  __shared__ unsigned short Vts[2][16 * 512];
  __shared__ unsigned short Ps[4][16 * PS_LD];

  const size_t qrow = (size_t)(b * S_LEN + q0 + wave * 16 + ln15) * QKV_N + h * HD;
  s16x8 qfrag[8];
#pragma unroll
  for (int f = 0; f < 8; ++f)
    qfrag[f] = *(const s16x8*)(qkv + qrow + f * 32 + lgr * 8);

  f32x4 acc[16];
#pragma unroll
  for (int t = 0; t < 16; ++t) acc[t] = (f32x4){0.f, 0.f, 0.f, 0.f};
  float l_part[4] = {0.f, 0.f, 0.f, 0.f};

  const int kt_lo = max(0, q0 - WIN) >> 5;
  const int kt_hi = (q0 + 63) >> 5;
  const unsigned short* kbase = qkv + (size_t)(b * S_LEN) * QKV_N + 4 * HD;
  const unsigned short* vbase = vtb + (size_t)b * (S_LEN / 32) * HD * 32;

  auto stage = [&](int kt, int buf) {
#pragma unroll
    for (int u = 0; u < 4; ++u) {
      const int c = wave * 4 + u;
      const int ct = c >> 3, f = c & 7;
      const unsigned short* gk =
          kbase + (size_t)(kt * 32 + ct * 16 + ln15) * QKV_N + f * 32 + lgr * 8;
      gl2lds16(gk, &Ks[buf][c * 512]);
      const unsigned short* gv =
          vbase + (size_t)kt * (HD * 32) + (size_t)(c * 16 + ln15) * 32 + lgr * 8;
      gl2lds16(gv, &Vts[buf][c * 512]);
    }
  };

  stage(kt_lo, 0);
  __syncthreads();

  unsigned short* psw = Ps[wave];
  const int i_row0 = q0 + wave * 16 + lgr * 4;

  for (int kt = kt_lo; kt <= kt_hi; ++kt) {
    const int cur = (kt - kt_lo) & 1;
    if (kt < kt_hi) stage(kt + 1, cur ^ 1);

    // QK^T
    f32x4 sc[2];
    sc[0] = (f32x4){0.f, 0.f, 0.f, 0.f};
    sc[1] = (f32x4){0.f, 0.f, 0.f, 0.f};
    __builtin_amdgcn_s_setprio(1);
#pragma unroll
    for (int f = 0; f < 8; ++f) {
#pragma unroll
      for (int ct = 0; ct < 2; ++ct) {
        const s16x8 kf = *(const s16x8*)&Ks[cur][(ct * 8 + f) * 512 + lane * 8];
        sc[ct] = __builtin_amdgcn_mfma_f32_16x16x32_bf16(qfrag[f], kf, sc[ct], 0, 0, 0);
      }
    }
    __builtin_amdgcn_s_setprio(0);

    // static-max softmax: p = exp(s - 16), masked to 0
    const int j0 = kt * 32 + ln15;
    float p0[4], p1[4];
#pragma unroll
    for (int r = 0; r < 4; ++r) {
      const int i = i_row0 + r;
      const bool a0 = (j0 <= i) && (i - j0 <= WIN);
      const bool a1 = (j0 + 16 <= i) && (i - (j0 + 16) <= WIN);
      const float e0 = __expf(sc[0][r] - 16.0f);
      const float e1 = __expf(sc[1][r] - 16.0f);
      p0[r] = a0 ? e0 : 0.0f;
      p1[r] = a1 ? e1 : 0.0f;
      l_part[r] += p0[r] + p1[r];
    }
    // packed b32 P writes: col 2*ln15 = key ln15 (ct0), col 2*ln15+1 = key 16+ln15
#pragma unroll
    for (int r = 0; r < 4; ++r) {
      const unsigned int pk = (unsigned int)f2bf(p0[r]) | ((unsigned int)f2bf(p1[r]) << 16);
      *(unsigned int*)&psw[(lgr * 4 + r) * PS_LD + (ln15 << 1)] = pk;
    }
    const s16x8 pf = *(const s16x8*)&psw[ln15 * PS_LD + lgr * 8];
    __builtin_amdgcn_s_setprio(1);
#pragma unroll
    for (int t = 0; t < 16; ++t) {
      const s16x8 vf = *(const s16x8*)&Vts[cur][t * 512 + lane * 8];
      acc[t] = __builtin_amdgcn_mfma_f32_16x16x32_bf16(pf, vf, acc[t], 0, 0, 0);
    }
    __builtin_amdgcn_s_setprio(0);
    __syncthreads();
  }

#pragma unroll
  for (int off = 1; off < 16; off <<= 1)
#pragma unroll
    for (int r = 0; r < 4; ++r) l_part[r] += __shfl_xor(l_part[r], off);

  float inv_l[4];
#pragma unroll
  for (int r = 0; r < 4; ++r) inv_l[r] = 1.0f / l_part[r];
#pragma unroll
  for (int t = 0; t < 16; ++t)
#pragma unroll
    for (int r = 0; r < 4; ++r) {
      const size_t orow = (size_t)(b * S_LEN + q0 + wave * 16 + lgr * 4 + r);
      aob[(orow * NH + h) * HD + t * 16 + ln15] = f2bf(acc[t][r] * inv_l[r]);
    }
}

// ---------------------------------------------------------------------------
extern "C" void kernel_launch(void* const* d_in, const int* in_sizes, int n_in,
                              void* d_out, int out_size, void* d_ws, size_t ws_size,
                              hipStream_t stream) {
  const float* x    = (const float*)d_in[0];
  const float* cosb = (const float*)d_in[1];
  const float* sinb = (const float*)d_in[2];
  const float* Wq   = (const float*)d_in[3];
  const float* Wk   = (const float*)d_in[4];
  const float* Wv   = (const float*)d_in[5];
  const float* Wo   = (const float*)d_in[6];
  const float* qw   = (const float*)d_in[7];
  const float* kw   = (const float*)d_in[8];
  float* out = (float*)d_out;

  unsigned short* ws = (unsigned short*)d_ws;
  unsigned short* xb     = ws;                    // 8192*640  = 5242880
  unsigned short* Wqkvt  = xb + 5242880;          // 1536*640  = 983040
  unsigned short* Wot    = Wqkvt + 983040;        // 640*1024  = 655360
  unsigned short* qkvb   = Wot + 655360;          // 8192*1536 = 12582912
  unsigned short* vtb    = qkvb + 12582912;       // 8192*256  = 2097152
  unsigned short* aob    = vtb + 2097152;         // 8192*1024 = 8388608
  const int M = 2 * S_LEN;

  prep_kernel<<<5520, 256, 0, stream>>>(x, xb, Wq, Wk, Wv, Wo, Wqkvt, Wot);
  gemm_bt<true><<<dim3(QKV_N / 128, M / 128), 256, 0, stream>>>(xb, Wqkvt, qkvb, M, QKV_N, 640);
  normrope_vt_kernel<<<10240 + 256, 256, 0, stream>>>(qkvb, cosb, sinb, qw, kw, vtb);
  attn_mfma_kernel<<<M / 64 * NH, 256, 0, stream>>>(qkvb, vtb, aob);
  gemm_bt64<<<dim3(640 / 128, M / 64), 256, 0, stream>>>(aob, Wot, out, M, 640, 1024);
}